// Round 4
// baseline (420.900 us; speedup 1.0000x reference)
//
#include <hip/hip_runtime.h>

typedef _Float16 f16x8 __attribute__((ext_vector_type(8)));
typedef float    f32x4 __attribute__((ext_vector_type(4)));

#define Bq   32
#define Lq   4096
#define Eq   1024
#define ROWS_OUT 2049               // cache_len + 1
#define TOT_G (Bq * ROWS_OUT)       // 65568 gemm rows (=16*4098)
#define TOT_C (Bq * (Lq - ROWS_OUT))// 65504 pure-copy rows
#define NGROUP 4098                 // TOT_G / 16
#define GBLK  256                   // blocks

#define LGKM_BARRIER() asm volatile("s_waitcnt lgkmcnt(0)\n\ts_barrier" ::: "memory")

// ---------------------------------------------------------------------------
// K1: vec[b][e] = inputA[b].W1a[e] + b1a[e] + inputB[b].W1b[e] + b1b[e]
// Wave per e; W rows in registers, loop over b (inputs L2-resident).
// ---------------------------------------------------------------------------
__global__ __launch_bounds__(256) void vec_kernel(
    const float* __restrict__ inA, const float* __restrict__ inB,
    const float* __restrict__ W1a, const float* __restrict__ b1a,
    const float* __restrict__ W1b, const float* __restrict__ b1b,
    float* __restrict__ vec)
{
    int e    = (blockIdx.x * 256 + threadIdx.x) >> 6;
    int lane = threadIdx.x & 63;
    if (e >= Eq) return;

    const float4* wa4 = (const float4*)(W1a + (size_t)e * Eq);
    const float4* wb4 = (const float4*)(W1b + (size_t)e * Eq);
    float4 wa[4], wb[4];
#pragma unroll
    for (int j = 0; j < 4; ++j) { wa[j] = wa4[lane + 64 * j]; wb[j] = wb4[lane + 64 * j]; }
    float bias = b1a[e] + b1b[e];

#pragma unroll 4
    for (int b = 0; b < Bq; ++b) {
        const float4* a4  = (const float4*)(inA + (size_t)b * Eq);
        const float4* bb4 = (const float4*)(inB + (size_t)b * Eq);
        float acc = 0.f;
#pragma unroll
        for (int j = 0; j < 4; ++j) {
            float4 a = a4[lane + 64 * j];
            acc += wa[j].x * a.x + wa[j].y * a.y + wa[j].z * a.z + wa[j].w * a.w;
            float4 v = bb4[lane + 64 * j];
            acc += wb[j].x * v.x + wb[j].y * v.y + wb[j].z * v.z + wb[j].w * v.w;
        }
#pragma unroll
        for (int s = 32; s; s >>= 1) acc += __shfl_xor(acc, s, 64);
        if (lane == 0) vec[(size_t)b * Eq + e] = acc + bias;
    }
}

// ---------------------------------------------------------------------------
// K2: symmetric fused kernel. 256 blocks x 1024 threads (16 waves).
// Per group iteration (grid-strided, double-buffered in registers):
//   - issue loads for group g+GBLK (16 gemm rows + 16 copy rows)  FIRST
//   - stores for group g: gemm rows f32 -> ncache, copy rows f32 -> ncache
//   - stage gemm rows f16 into XOR-swizzled LDS rowbuf
//   - lgkm barrier; MFMA 16x16x32_f16: wave (n,q) = N-tile n, K-quarter q,
//     W2 f16 B-fragments resident in 32 VGPRs/wave; part-write; lgkm barrier
//   - q==0 waves reduce 4 K-quarters + bias -> out
// Loads always precede stores in the per-wave vmem queue, so vmcnt waits for
// prefetched data never wait on stores; ~128KB/CU stays in flight.
// ---------------------------------------------------------------------------
__global__ __launch_bounds__(1024, 4) void mega_kernel(
    const float* __restrict__ cache, const float* __restrict__ vec,
    const float* __restrict__ W2, const float* __restrict__ b2,
    float* __restrict__ outp, float* __restrict__ ncache)
{
    __shared__ _Float16 rowbuf_raw[16 * Eq];   // 32 KB
    __shared__ float    part[12 * 64 * 4];     // 12 KB

    const int tid = threadIdx.x;
    const int w = tid >> 6, l = tid & 63;
    const int n = w >> 2, q = w & 3;           // N-tile, K-quarter
    char* rb = (char*)rowbuf_raw;

    // B fragments: lane l holds W2[o=16n+(l&15)][k=(8q+s)*32+(l>>4)*8 + j]
    f16x8 bfr[8];
    {
        const float* wrow = W2 + (size_t)(16 * n + (l & 15)) * Eq;
#pragma unroll
        for (int s = 0; s < 8; ++s) {
            int k0 = (q * 8 + s) * 32 + (l >> 4) * 8;
            float4 x = *(const float4*)(wrow + k0);
            float4 y = *(const float4*)(wrow + k0 + 4);
            f16x8 v;
            v[0] = (_Float16)x.x; v[1] = (_Float16)x.y; v[2] = (_Float16)x.z; v[3] = (_Float16)x.w;
            v[4] = (_Float16)y.x; v[5] = (_Float16)y.y; v[6] = (_Float16)y.z; v[7] = (_Float16)y.w;
            bfr[s] = v;
        }
    }
    const float bias = b2[16 * n + (l & 15)];

    auto issue_loads = [&](int g, float4 (&gl)[4], float4 (&cl)[4]) {
        int R = g * 16 + w;                          // gemm row (always < TOT_G)
        int bb = R / ROWS_OUT, t = R - bb * ROWS_OUT;
        const float* srcG = (t == ROWS_OUT - 1) ? (vec + (size_t)bb * Eq)
                                                : (cache + ((size_t)bb * Lq + t) * Eq);
        const float4* s4 = (const float4*)srcG;
#pragma unroll
        for (int j = 0; j < 4; ++j) gl[j] = s4[4 * l + j];
        if (R < TOT_C) {                             // copy row
            int cb = R / (Lq - ROWS_OUT), tc = ROWS_OUT + R - cb * (Lq - ROWS_OUT);
            const float4* c4 = (const float4*)(cache + ((size_t)cb * Lq + tc) * Eq);
#pragma unroll
            for (int j = 0; j < 4; ++j) cl[j] = c4[4 * l + j];
        }
    };

    auto body = [&](int g, float4 (&gl)[4], float4 (&cl)[4],
                    float4 (&gl2)[4], float4 (&cl2)[4]) {
        // ---- loads first (prefetch g+GBLK) ----
        if (g + GBLK < NGROUP) issue_loads(g + GBLK, gl2, cl2);

        // ---- stores for g (waits only on g's loads, not on any stores) ----
        {
            int R = g * 16 + w;
            int bb = R / ROWS_OUT, t = R - bb * ROWS_OUT;
            float4* d4 = (float4*)(ncache + ((size_t)bb * Lq + t) * Eq);
#pragma unroll
            for (int j = 0; j < 4; ++j) d4[4 * l + j] = gl[j];
            if (R < TOT_C) {
                int cb = R / (Lq - ROWS_OUT), tc = ROWS_OUT + R - cb * (Lq - ROWS_OUT);
                float4* c4 = (float4*)(ncache + ((size_t)cb * Lq + tc) * Eq);
#pragma unroll
                for (int j = 0; j < 4; ++j) c4[4 * l + j] = cl[j];
            }
            // f16 stage into swizzled rowbuf: row w, f32 cols [16l,16l+16)
            f16x8 h0, h1;
            h0[0] = (_Float16)gl[0].x; h0[1] = (_Float16)gl[0].y;
            h0[2] = (_Float16)gl[0].z; h0[3] = (_Float16)gl[0].w;
            h0[4] = (_Float16)gl[1].x; h0[5] = (_Float16)gl[1].y;
            h0[6] = (_Float16)gl[1].z; h0[7] = (_Float16)gl[1].w;
            h1[0] = (_Float16)gl[2].x; h1[1] = (_Float16)gl[2].y;
            h1[2] = (_Float16)gl[2].z; h1[3] = (_Float16)gl[2].w;
            h1[4] = (_Float16)gl[3].x; h1[5] = (_Float16)gl[3].y;
            h1[6] = (_Float16)gl[3].z; h1[7] = (_Float16)gl[3].w;
            int base = w * 2048 + l * 32;
            int swz  = (w & 7) << 4;
            *(f16x8*)(rb + (base ^ swz))        = h0;
            *(f16x8*)(rb + ((base + 16) ^ swz)) = h1;
        }

        LGKM_BARRIER();   // rowbuf ready; global ops stay in flight

        // ---- MFMA: A from LDS (swizzled), B resident ----
        f32x4 acc = {0.f, 0.f, 0.f, 0.f};
        {
            const int m    = l & 15;
            const int aswz = (m & 7) << 4;
            const int rbase = m * 2048 + (l >> 4) * 16;
#pragma unroll
            for (int s = 0; s < 8; ++s) {
                int sa = q * 8 + s;
                f16x8 afr = *(const f16x8*)(rb + ((rbase + sa * 64) ^ aswz));
                acc = __builtin_amdgcn_mfma_f32_16x16x32_f16(afr, bfr[s], acc, 0, 0, 0);
            }
        }
        if (q) *(f32x4*)&part[((n * 3 + q - 1) * 64 + l) * 4] = acc;

        LGKM_BARRIER();   // partials ready

        if (q == 0) {
#pragma unroll
            for (int j = 0; j < 3; ++j)
                acc += *(const f32x4*)&part[((n * 3 + j) * 64 + l) * 4];
            int R0 = g * 16 + (l >> 4) * 4;        // C row = (lane>>4)*4 + reg
            float* op = outp + (size_t)R0 * 64 + 16 * n + (l & 15);
#pragma unroll
            for (int r = 0; r < 4; ++r) op[(size_t)r * 64] = acc[r] + bias;
        }
    };

    float4 gA[4], cA[4], gB[4], cB[4];
    int g0 = blockIdx.x;
    issue_loads(g0, gA, cA);
    for (int g = g0; g < NGROUP; g += 2 * GBLK) {
        body(g, gA, cA, gB, cB);
        if (g + GBLK < NGROUP) body(g + GBLK, gB, cB, gA, cA);
    }
}

// ---------------------------------------------------------------------------
extern "C" void kernel_launch(void* const* d_in, const int* in_sizes, int n_in,
                              void* d_out, int out_size, void* d_ws, size_t ws_size,
                              hipStream_t stream)
{
    const float* inA   = (const float*)d_in[0];
    const float* inB   = (const float*)d_in[1];
    const float* cache = (const float*)d_in[2];
    const float* W1a   = (const float*)d_in[3];
    const float* b1a   = (const float*)d_in[4];
    const float* W1b   = (const float*)d_in[5];
    const float* b1b   = (const float*)d_in[6];
    const float* W2    = (const float*)d_in[7];
    const float* b2v   = (const float*)d_in[8];

    float* outp   = (float*)d_out;                       // (B,2049,64) then (B,L,E)
    float* ncache = outp + (size_t)Bq * ROWS_OUT * 64;
    float* vecbuf = (float*)d_ws;                        // 32*1024 f32

    vec_kernel<<<dim3(256), dim3(256), 0, stream>>>(inA, inB, W1a, b1a, W1b, b1b, vecbuf);

    mega_kernel<<<dim3(GBLK), dim3(1024), 0, stream>>>(cache, vecbuf, W2, b2v,
                                                       outp, ncache);
}

// Round 5
// 378.473 us; speedup vs baseline: 1.1121x; 1.1121x over previous
//
#include <hip/hip_runtime.h>

typedef _Float16 f16x8 __attribute__((ext_vector_type(8)));
typedef float    f32x4 __attribute__((ext_vector_type(4)));

#define Bq   32
#define Lq   4096
#define Eq   1024
#define ROWS_OUT 2049                 // cache_len + 1
#define SPANC (Lq - ROWS_OUT)         // 2047 pure-copy rows per batch
#define TOT_G (Bq * ROWS_OUT)         // 65568 gemm rows (= 16 * 4098)
#define TOT_C (Bq * SPANC)            // 65504 pure-copy rows
#define NGROUP (TOT_G / 16)           // 4098
#define GBLK  256                     // blocks

#define LGKM_BARRIER() asm volatile("s_waitcnt lgkmcnt(0)\n\ts_barrier" ::: "memory")

// ---------------------------------------------------------------------------
// K1: vec[b][e] = inputA[b].W1a[e] + b1a[e] + inputB[b].W1b[e] + b1b[e]
// Wave per e; W rows in registers, loop over b (inputs L1/L2-resident).
// ---------------------------------------------------------------------------
__global__ __launch_bounds__(256) void vec_kernel(
    const float* __restrict__ inA, const float* __restrict__ inB,
    const float* __restrict__ W1a, const float* __restrict__ b1a,
    const float* __restrict__ W1b, const float* __restrict__ b1b,
    float* __restrict__ vec)
{
    int e    = (blockIdx.x * 256 + threadIdx.x) >> 6;
    int lane = threadIdx.x & 63;
    if (e >= Eq) return;

    const float4* wa4 = (const float4*)(W1a + (size_t)e * Eq);
    const float4* wb4 = (const float4*)(W1b + (size_t)e * Eq);
    float4 wa[4], wb[4];
#pragma unroll
    for (int j = 0; j < 4; ++j) { wa[j] = wa4[lane + 64 * j]; wb[j] = wb4[lane + 64 * j]; }
    float bias = b1a[e] + b1b[e];

#pragma unroll 4
    for (int b = 0; b < Bq; ++b) {
        const float4* a4  = (const float4*)(inA + (size_t)b * Eq);
        const float4* bb4 = (const float4*)(inB + (size_t)b * Eq);
        float acc = 0.f;
#pragma unroll
        for (int j = 0; j < 4; ++j) {
            float4 a = a4[lane + 64 * j];
            acc += wa[j].x * a.x + wa[j].y * a.y + wa[j].z * a.z + wa[j].w * a.w;
            float4 v = bb4[lane + 64 * j];
            acc += wb[j].x * v.x + wb[j].y * v.y + wb[j].z * v.z + wb[j].w * v.w;
        }
#pragma unroll
        for (int s = 32; s; s >>= 1) acc += __shfl_xor(acc, s, 64);
        if (lane == 0) vec[(size_t)b * Eq + e] = acc + bias;
    }
}

// ---------------------------------------------------------------------------
// K2: symmetric fused kernel, spill-free double buffer in NAMED registers.
// 256 blocks x 1024 threads (16 waves = 4 N-tiles x 4 K-quarters).
// Per group g (16 gemm rows + 16 copy rows):
//   loads(g+GBLK) -> stores(g) -> f16 LDS stage -> lgkm barrier ->
//   MFMA 16x16x32_f16 (W2 f16 B-frags resident, 32 VGPR/wave) ->
//   part write -> lgkm barrier -> q==0 reduce + out store.
// Loads always precede stores in the per-wave vmem queue => prefetched data
// never waits on store acks; global ops stay in flight across barriers.
// ---------------------------------------------------------------------------

#define FETCH_G(g_, p0, p1, p2, p3)                                            \
  { int R_ = (g_) * 16 + w;                                                    \
    int bb_ = R_ / ROWS_OUT;                                                   \
    int t_  = R_ - bb_ * ROWS_OUT;                                             \
    const float4* s4_ = (const float4*)((t_ == ROWS_OUT - 1)                   \
        ? (vec + (size_t)bb_ * Eq)                                             \
        : (cache + ((size_t)bb_ * Lq + t_) * Eq));                             \
    p0 = s4_[4 * l + 0]; p1 = s4_[4 * l + 1];                                  \
    p2 = s4_[4 * l + 2]; p3 = s4_[4 * l + 3]; }

#define FETCH_C(g_, p0, p1, p2, p3)                                            \
  { int R_ = (g_) * 16 + w;                                                    \
    if (R_ < TOT_C) {                                                          \
      int cb_ = R_ / SPANC;                                                    \
      int tc_ = ROWS_OUT + R_ - cb_ * SPANC;                                   \
      const float4* c4_ = (const float4*)(cache + ((size_t)cb_ * Lq + tc_) * Eq); \
      p0 = c4_[4 * l + 0]; p1 = c4_[4 * l + 1];                                \
      p2 = c4_[4 * l + 2]; p3 = c4_[4 * l + 3]; } }

#define BODY(g_, gl0, gl1, gl2, gl3, cl0, cl1, cl2, cl3,                       \
             pg0, pg1, pg2, pg3, pc0, pc1, pc2, pc3)                           \
  {                                                                            \
    if ((g_) + GBLK < NGROUP) {                                                \
      FETCH_G((g_) + GBLK, pg0, pg1, pg2, pg3);                                \
      FETCH_C((g_) + GBLK, pc0, pc1, pc2, pc3);                                \
    }                                                                          \
    {                                                                          \
      int R_ = (g_) * 16 + w;                                                  \
      int bb_ = R_ / ROWS_OUT;                                                 \
      int t_  = R_ - bb_ * ROWS_OUT;                                           \
      float4* d4_ = (float4*)(ncache + ((size_t)bb_ * Lq + t_) * Eq);          \
      d4_[4 * l + 0] = gl0; d4_[4 * l + 1] = gl1;                              \
      d4_[4 * l + 2] = gl2; d4_[4 * l + 3] = gl3;                              \
      if (R_ < TOT_C) {                                                        \
        int cb_ = R_ / SPANC;                                                  \
        int tc_ = ROWS_OUT + R_ - cb_ * SPANC;                                 \
        float4* c4_ = (float4*)(ncache + ((size_t)cb_ * Lq + tc_) * Eq);       \
        c4_[4 * l + 0] = cl0; c4_[4 * l + 1] = cl1;                            \
        c4_[4 * l + 2] = cl2; c4_[4 * l + 3] = cl3;                            \
      }                                                                        \
      f16x8 h0_, h1_;                                                          \
      h0_[0] = (_Float16)gl0.x; h0_[1] = (_Float16)gl0.y;                      \
      h0_[2] = (_Float16)gl0.z; h0_[3] = (_Float16)gl0.w;                      \
      h0_[4] = (_Float16)gl1.x; h0_[5] = (_Float16)gl1.y;                      \
      h0_[6] = (_Float16)gl1.z; h0_[7] = (_Float16)gl1.w;                      \
      h1_[0] = (_Float16)gl2.x; h1_[1] = (_Float16)gl2.y;                      \
      h1_[2] = (_Float16)gl2.z; h1_[3] = (_Float16)gl2.w;                      \
      h1_[4] = (_Float16)gl3.x; h1_[5] = (_Float16)gl3.y;                      \
      h1_[6] = (_Float16)gl3.z; h1_[7] = (_Float16)gl3.w;                      \
      int base_ = w * 2048 + l * 32;                                           \
      int swz_  = (w & 7) << 4;                                                \
      *(f16x8*)(rb + (base_ ^ swz_))        = h0_;                             \
      *(f16x8*)(rb + ((base_ + 16) ^ swz_)) = h1_;                             \
    }                                                                          \
    LGKM_BARRIER();                                                            \
    {                                                                          \
      f32x4 acc_ = {0.f, 0.f, 0.f, 0.f};                                       \
      const int m_ = l & 15;                                                   \
      const int aswz_ = (m_ & 7) << 4;                                         \
      const int rbase_ = m_ * 2048 + (l >> 4) * 16;                            \
      _Pragma("unroll")                                                        \
      for (int s_ = 0; s_ < 8; ++s_) {                                         \
        int sa_ = q * 8 + s_;                                                  \
        f16x8 afr_ = *(const f16x8*)(rb + ((rbase_ + sa_ * 64) ^ aswz_));      \
        acc_ = __builtin_amdgcn_mfma_f32_16x16x32_f16(afr_, bfr[s_], acc_, 0, 0, 0); \
      }                                                                        \
      if (q) *(f32x4*)&part[((n * 3 + q - 1) * 64 + l) * 4] = acc_;            \
      LGKM_BARRIER();                                                          \
      if (q == 0) {                                                            \
        _Pragma("unroll")                                                      \
        for (int j_ = 0; j_ < 3; ++j_)                                         \
          acc_ += *(const f32x4*)&part[((n * 3 + j_) * 64 + l) * 4];           \
        int R0_ = (g_) * 16 + (l >> 4) * 4;                                    \
        float* op_ = outp + (size_t)R0_ * 64 + 16 * n + m_;                    \
        op_[0]   = acc_[0] + bias; op_[64]  = acc_[1] + bias;                  \
        op_[128] = acc_[2] + bias; op_[192] = acc_[3] + bias;                  \
      }                                                                        \
    }                                                                          \
  }

__global__ __launch_bounds__(1024, 4) void mega_kernel(
    const float* __restrict__ cache, const float* __restrict__ vec,
    const float* __restrict__ W2, const float* __restrict__ b2,
    float* __restrict__ outp, float* __restrict__ ncache)
{
    __shared__ _Float16 rowbuf_raw[16 * Eq];   // 32 KB
    __shared__ float    part[12 * 64 * 4];     // 12 KB

    const int tid = threadIdx.x;
    const int w = tid >> 6, l = tid & 63;
    const int n = w >> 2, q = w & 3;           // N-tile, K-quarter
    char* rb = (char*)rowbuf_raw;

    // B fragments: lane l holds W2[o=16n+(l&15)][k=(8q+s)*32+(l>>4)*8 + j]
    f16x8 bfr[8];
#pragma unroll
    for (int s = 0; s < 8; ++s) {
        const float* wrow = W2 + (size_t)(16 * n + (l & 15)) * Eq;
        int k0 = (q * 8 + s) * 32 + (l >> 4) * 8;
        float4 x = *(const float4*)(wrow + k0);
        float4 y = *(const float4*)(wrow + k0 + 4);
        f16x8 v;
        v[0] = (_Float16)x.x; v[1] = (_Float16)x.y; v[2] = (_Float16)x.z; v[3] = (_Float16)x.w;
        v[4] = (_Float16)y.x; v[5] = (_Float16)y.y; v[6] = (_Float16)y.z; v[7] = (_Float16)y.w;
        bfr[s] = v;
    }
    const float bias = b2[16 * n + (l & 15)];

    float4 z = {0.f, 0.f, 0.f, 0.f};
    float4 ga0 = z, ga1 = z, ga2 = z, ga3 = z, ca0 = z, ca1 = z, ca2 = z, ca3 = z;
    float4 gb0 = z, gb1 = z, gb2 = z, gb3 = z, cb0 = z, cb1 = z, cb2 = z, cb3 = z;

    int g0 = blockIdx.x;
    FETCH_G(g0, ga0, ga1, ga2, ga3);
    FETCH_C(g0, ca0, ca1, ca2, ca3);

#pragma unroll 1
    for (int g = g0; g < NGROUP; ) {
        BODY(g, ga0, ga1, ga2, ga3, ca0, ca1, ca2, ca3,
                gb0, gb1, gb2, gb3, cb0, cb1, cb2, cb3);
        g += GBLK;
        if (g >= NGROUP) break;
        BODY(g, gb0, gb1, gb2, gb3, cb0, cb1, cb2, cb3,
                ga0, ga1, ga2, ga3, ca0, ca1, ca2, ca3);
        g += GBLK;
    }
}

// ---------------------------------------------------------------------------
extern "C" void kernel_launch(void* const* d_in, const int* in_sizes, int n_in,
                              void* d_out, int out_size, void* d_ws, size_t ws_size,
                              hipStream_t stream)
{
    const float* inA   = (const float*)d_in[0];
    const float* inB   = (const float*)d_in[1];
    const float* cache = (const float*)d_in[2];
    const float* W1a   = (const float*)d_in[3];
    const float* b1a   = (const float*)d_in[4];
    const float* W1b   = (const float*)d_in[5];
    const float* b1b   = (const float*)d_in[6];
    const float* W2    = (const float*)d_in[7];
    const float* b2v   = (const float*)d_in[8];

    float* outp   = (float*)d_out;                       // (B,2049,64) then (B,L,E)
    float* ncache = outp + (size_t)Bq * ROWS_OUT * 64;
    float* vecbuf = (float*)d_ws;                        // 32*1024 f32

    vec_kernel<<<dim3(256), dim3(256), 0, stream>>>(inA, inB, W1a, b1a, W1b, b1b, vecbuf);

    mega_kernel<<<dim3(GBLK), dim3(1024), 0, stream>>>(cache, vecbuf, W2, b2v,
                                                       outp, ncache);
}